// Round 1
// baseline (1079.108 us; speedup 1.0000x reference)
//
#include <hip/hip_runtime.h>
#include <hip/hip_bf16.h>

// Problem constants (match reference)
#define N_NODES 100000
#define N_EDGES 1600000
#define N_GRAPHS 128

// ---------------- CSR build ----------------

__global__ void k_count(const int* __restrict__ col, int* __restrict__ deg) {
    int e = blockIdx.x * blockDim.x + threadIdx.x;
    if (e < N_EDGES) atomicAdd(&deg[col[e]], 1);
}

// per-block exclusive scan over 256 elements
__global__ void k_scan1(const int* __restrict__ deg, int* __restrict__ offs,
                        int* __restrict__ bsums) {
    __shared__ int s[256];
    int t = threadIdx.x;
    int gi = blockIdx.x * 256 + t;
    int v = (gi < N_NODES) ? deg[gi] : 0;
    s[t] = v; __syncthreads();
    for (int off = 1; off < 256; off <<= 1) {
        int a = (t >= off) ? s[t - off] : 0;
        __syncthreads();
        s[t] += a;
        __syncthreads();
    }
    if (gi < N_NODES) offs[gi] = s[t] - v;   // exclusive
    if (t == 255) bsums[blockIdx.x] = s[255];
}

// scan the 391 block sums (single block, Hillis-Steele over 512)
__global__ void k_scan2(int* __restrict__ bsums, int nb) {
    __shared__ int s[512];
    int t = threadIdx.x;
    int v = (t < nb) ? bsums[t] : 0;
    s[t] = v; __syncthreads();
    for (int off = 1; off < 512; off <<= 1) {
        int a = (t >= off) ? s[t - off] : 0;
        __syncthreads();
        s[t] += a;
        __syncthreads();
    }
    if (t < nb) bsums[t] = s[t] - v;         // exclusive
}

__global__ void k_scan3(int* __restrict__ offs, const int* __restrict__ bsums,
                        const int* __restrict__ deg, int* __restrict__ cursor,
                        float* __restrict__ dinv) {
    int gi = blockIdx.x * 256 + threadIdx.x;
    if (gi >= N_NODES) return;
    int off = offs[gi] + bsums[blockIdx.x];
    offs[gi] = off;
    cursor[gi] = off;
    int d = deg[gi];
    dinv[gi] = (d > 0) ? rsqrtf((float)d) : 0.0f;
}

__global__ void k_scatter(const int* __restrict__ row, const int* __restrict__ col,
                          const float* __restrict__ dinv, int* __restrict__ cursor,
                          int2* __restrict__ csr) {
    int e = blockIdx.x * blockDim.x + threadIdx.x;
    if (e >= N_EDGES) return;
    int r = row[e], c = col[e];
    int pos = atomicAdd(&cursor[c], 1);
    csr[pos] = make_int2(r, __float_as_int(dinv[r] * dinv[c]));
}

// ---------------- tall-skinny GEMM: H[N,64] = X[N,CIN] @ W[CIN,64] ----------------
// block = 256 threads = 4 waves; each wave does 8 nodes, lane = output channel.

template <int CIN>
__global__ __launch_bounds__(256) void k_gemm(const float* __restrict__ X,
                                              const float* __restrict__ W,
                                              float* __restrict__ H) {
    constexpr int STR = CIN + 4;               // pad to break bank alias
    __shared__ float sW[64 * STR];             // W transposed: sW[c*STR + k]
    __shared__ float sX[32 * STR];             // 32 nodes of X
    const int t = threadIdx.x;

    for (int idx = t; idx < CIN * 64; idx += 256) {
        int k = idx >> 6, c = idx & 63;
        sW[c * STR + k] = W[idx];
    }
    const int nb = blockIdx.x * 32;
    for (int f4 = t; f4 < 32 * CIN / 4; f4 += 256) {
        int f = f4 * 4;
        int nl = f / CIN, kk = f % CIN;
        const float4 v = *reinterpret_cast<const float4*>(X + (size_t)(nb + nl) * CIN + kk);
        *reinterpret_cast<float4*>(&sX[nl * STR + kk]) = v;
    }
    __syncthreads();

    const int wave = t >> 6, lane = t & 63;
    const int n0 = wave * 8;
    float acc[8] = {0.f,0.f,0.f,0.f,0.f,0.f,0.f,0.f};
    for (int kq = 0; kq < CIN; kq += 4) {
        const float4 w4 = *reinterpret_cast<const float4*>(&sW[lane * STR + kq]);
        #pragma unroll
        for (int n = 0; n < 8; n++) {
            const float4 x4 = *reinterpret_cast<const float4*>(&sX[(n0 + n) * STR + kq]);
            acc[n] += w4.x * x4.x + w4.y * x4.y + w4.z * x4.z + w4.w * x4.w;
        }
    }
    #pragma unroll
    for (int n = 0; n < 8; n++) {
        H[(size_t)(nb + n0 + n) * 64 + lane] = acc[n];
    }
}

// ---------------- propagation: Hout[v] = sum_e norm_e * Hin[row_e] + bias ----------------
// one wave per node, lane = channel

__global__ __launch_bounds__(256) void k_prop(const float* __restrict__ Hin,
                                              const int2* __restrict__ csr,
                                              const int* __restrict__ offs,
                                              const int* __restrict__ deg,
                                              const float* __restrict__ bias,
                                              float* __restrict__ Hout) {
    const int wave = threadIdx.x >> 6, lane = threadIdx.x & 63;
    const int v = blockIdx.x * 4 + wave;
    if (v >= N_NODES) return;
    const int start = offs[v];
    const int cnt = deg[v];
    float acc = 0.f;
    for (int j = 0; j < cnt; j++) {
        const int2 p = csr[start + j];                  // wave-uniform broadcast load
        acc += __int_as_float(p.y) * Hin[(size_t)p.x * 64 + lane];
    }
    Hout[(size_t)v * 64 + lane] = acc + bias[lane];
}

// ---------------- pooling ----------------

__global__ void k_pool(const float* __restrict__ H, const int* __restrict__ batch,
                       float* __restrict__ gsums) {
    const int gw = (blockIdx.x * blockDim.x + threadIdx.x) >> 6;
    const int lane = threadIdx.x & 63;
    const int nwaves = (gridDim.x * blockDim.x) >> 6;
    const int chunk = (N_NODES + nwaves - 1) / nwaves;
    int v0 = gw * chunk;
    int v1 = min(v0 + chunk, N_NODES);
    if (v0 >= v1) return;
    float acc = 0.f;
    int cur = batch[v0];
    for (int v = v0; v < v1; v++) {
        int g = batch[v];
        if (g != cur) {
            atomicAdd(&gsums[cur * 64 + lane], acc);
            acc = 0.f; cur = g;
        }
        acc += H[(size_t)v * 64 + lane];
    }
    atomicAdd(&gsums[cur * 64 + lane], acc);
}

__global__ void k_counts(const int* __restrict__ batch, int* __restrict__ gcounts) {
    int t = threadIdx.x;
    if (t >= N_GRAPHS) return;
    // lower_bound(batch, t) and lower_bound(batch, t+1)
    int lo = 0, hi = N_NODES;
    while (lo < hi) { int mid = (lo + hi) >> 1; if (batch[mid] < t) lo = mid + 1; else hi = mid; }
    int a = lo;
    lo = 0; hi = N_NODES;
    while (lo < hi) { int mid = (lo + hi) >> 1; if (batch[mid] < t + 1) lo = mid + 1; else hi = mid; }
    gcounts[t] = lo - a;
}

__global__ void k_final(const float* __restrict__ gsums, const int* __restrict__ gcounts,
                        const float* __restrict__ Wl, const float* __restrict__ bl,
                        float* __restrict__ out) {
    __shared__ int smax[128];
    int t = threadIdx.x;
    smax[t] = gcounts[t];
    __syncthreads();
    for (int off = 64; off > 0; off >>= 1) {
        if (t < off) smax[t] = max(smax[t], smax[t + off]);
        __syncthreads();
    }
    float nmax = (float)smax[0];
    float s = 0.f;
    for (int c = 0; c < 64; c++) s += gsums[(size_t)t * 64 + c] * Wl[c];
    out[t] = s / nmax + bl[0];
}

// ---------------- launch ----------------

extern "C" void kernel_launch(void* const* d_in, const int* in_sizes, int n_in,
                              void* d_out, int out_size, void* d_ws, size_t ws_size,
                              hipStream_t stream) {
    const float* x    = (const float*)d_in[0];
    const int*   ei   = (const int*)d_in[1];     // [2, E] int32
    const int*   batch= (const int*)d_in[2];
    const float* W1 = (const float*)d_in[3];  const float* b1 = (const float*)d_in[4];
    const float* W2 = (const float*)d_in[5];  const float* b2 = (const float*)d_in[6];
    const float* W3 = (const float*)d_in[7];  const float* b3 = (const float*)d_in[8];
    const float* W4 = (const float*)d_in[9];  const float* b4 = (const float*)d_in[10];
    const float* Wl = (const float*)d_in[11]; const float* bl = (const float*)d_in[12];
    float* out = (float*)d_out;

    const int* row = ei;
    const int* col = ei + N_EDGES;

    // workspace layout (256B aligned blocks)
    char* ws = (char*)d_ws;
    size_t off = 0;
    auto alloc = [&](size_t bytes) {
        void* p = ws + off;
        off = (off + bytes + 255) & ~(size_t)255;
        return p;
    };
    int*   deg     = (int*)alloc(N_NODES * 4);
    int*   offs    = (int*)alloc(N_NODES * 4);
    int*   cursor  = (int*)alloc(N_NODES * 4);
    float* dinv    = (float*)alloc(N_NODES * 4);
    int*   bsums   = (int*)alloc(512 * 4);
    int2*  csr     = (int2*)alloc((size_t)N_EDGES * 8);
    float* h_a     = (float*)alloc((size_t)N_NODES * 64 * 4);
    float* h_b     = (float*)alloc((size_t)N_NODES * 64 * 4);
    float* gsums   = (float*)alloc(N_GRAPHS * 64 * 4);
    int*   gcounts = (int*)alloc(N_GRAPHS * 4);

    const int SCAN_BLOCKS = (N_NODES + 255) / 256;   // 391

    hipMemsetAsync(deg, 0, N_NODES * 4, stream);
    hipMemsetAsync(gsums, 0, N_GRAPHS * 64 * 4, stream);

    k_count<<<(N_EDGES + 255) / 256, 256, 0, stream>>>(col, deg);
    k_scan1<<<SCAN_BLOCKS, 256, 0, stream>>>(deg, offs, bsums);
    k_scan2<<<1, 512, 0, stream>>>(bsums, SCAN_BLOCKS);
    k_scan3<<<SCAN_BLOCKS, 256, 0, stream>>>(offs, bsums, deg, cursor, dinv);
    k_scatter<<<(N_EDGES + 255) / 256, 256, 0, stream>>>(row, col, dinv, cursor, csr);

    // layer 1: h_a = x @ W1 ; h_b = prop(h_a) + b1
    k_gemm<128><<<N_NODES / 32, 256, 0, stream>>>(x, W1, h_a);
    k_prop<<<N_NODES / 4, 256, 0, stream>>>(h_a, csr, offs, deg, b1, h_b);
    // layer 2
    k_gemm<64><<<N_NODES / 32, 256, 0, stream>>>(h_b, W2, h_a);
    k_prop<<<N_NODES / 4, 256, 0, stream>>>(h_a, csr, offs, deg, b2, h_b);
    // layer 3
    k_gemm<64><<<N_NODES / 32, 256, 0, stream>>>(h_b, W3, h_a);
    k_prop<<<N_NODES / 4, 256, 0, stream>>>(h_a, csr, offs, deg, b3, h_b);
    // layer 4
    k_gemm<64><<<N_NODES / 32, 256, 0, stream>>>(h_b, W4, h_a);
    k_prop<<<N_NODES / 4, 256, 0, stream>>>(h_a, csr, offs, deg, b4, h_b);

    // pooling + readout
    k_counts<<<1, 128, 0, stream>>>(batch, gcounts);
    k_pool<<<98, 256, 0, stream>>>(h_b, batch, gsums);
    k_final<<<1, 128, 0, stream>>>(gsums, gcounts, Wl, bl, out);
}

// Round 2
// 787.888 us; speedup vs baseline: 1.3696x; 1.3696x over previous
//
#include <hip/hip_runtime.h>
#include <hip/hip_bf16.h>

// Problem constants (match reference)
#define N_NODES 100000
#define N_EDGES 1600000
#define N_GRAPHS 128

// ---------------- CSR build ----------------

__global__ void k_count(const int* __restrict__ col, int* __restrict__ deg) {
    int e = blockIdx.x * blockDim.x + threadIdx.x;
    if (e < N_EDGES) atomicAdd(&deg[col[e]], 1);
}

// per-block exclusive scan over 256 PADDED degrees (pad to multiple of 8)
__global__ void k_scan1(const int* __restrict__ deg, int* __restrict__ offs,
                        int* __restrict__ bsums) {
    __shared__ int s[256];
    int t = threadIdx.x;
    int gi = blockIdx.x * 256 + t;
    int v = (gi < N_NODES) ? ((deg[gi] + 7) & ~7) : 0;
    s[t] = v; __syncthreads();
    for (int off = 1; off < 256; off <<= 1) {
        int a = (t >= off) ? s[t - off] : 0;
        __syncthreads();
        s[t] += a;
        __syncthreads();
    }
    if (gi < N_NODES) offs[gi] = s[t] - v;   // exclusive
    if (t == 255) bsums[blockIdx.x] = s[255];
}

// scan the block sums (single block, Hillis-Steele over 512)
__global__ void k_scan2(int* __restrict__ bsums, int nb) {
    __shared__ int s[512];
    int t = threadIdx.x;
    int v = (t < nb) ? bsums[t] : 0;
    s[t] = v; __syncthreads();
    for (int off = 1; off < 512; off <<= 1) {
        int a = (t >= off) ? s[t - off] : 0;
        __syncthreads();
        s[t] += a;
        __syncthreads();
    }
    if (t < nb) bsums[t] = s[t] - v;         // exclusive
}

// finalize offsets, cursors, dinv; fill the padding slots with the sentinel
// zero-row index (N_NODES). Safe to do before k_scatter: disjoint positions.
__global__ void k_scan3(int* __restrict__ offs, const int* __restrict__ bsums,
                        const int* __restrict__ deg, int* __restrict__ cursor,
                        float* __restrict__ dinv, int* __restrict__ csr) {
    int gi = blockIdx.x * 256 + threadIdx.x;
    if (gi >= N_NODES) return;
    int off = offs[gi] + bsums[blockIdx.x];
    offs[gi] = off;
    cursor[gi] = off;
    int d = deg[gi];
    dinv[gi] = (d > 0) ? rsqrtf((float)d) : 0.0f;
    int pd = (d + 7) & ~7;
    for (int j = d; j < pd; j++) csr[off + j] = N_NODES;   // sentinel -> zero row
}

__global__ void k_scatter(const int* __restrict__ row, const int* __restrict__ col,
                          int* __restrict__ cursor, int* __restrict__ csr) {
    int e = blockIdx.x * blockDim.x + threadIdx.x;
    if (e >= N_EDGES) return;
    int r = row[e], c = col[e];
    int pos = atomicAdd(&cursor[c], 1);
    csr[pos] = r;
}

// ---------------- tall-skinny GEMM: H[n] = dinv[n] * (X[n,:] @ W) ----------------
// block = 256 threads = 4 waves; each wave does 8 nodes, lane = output channel.

template <int CIN>
__global__ __launch_bounds__(256) void k_gemm(const float* __restrict__ X,
                                              const float* __restrict__ W,
                                              const float* __restrict__ dinv,
                                              float* __restrict__ H) {
    constexpr int STR = CIN + 4;               // pad to break bank alias
    __shared__ float sW[64 * STR];             // W transposed: sW[c*STR + k]
    __shared__ float sX[32 * STR];             // 32 nodes of X
    const int t = threadIdx.x;

    for (int idx = t; idx < CIN * 64; idx += 256) {
        int k = idx >> 6, c = idx & 63;
        sW[c * STR + k] = W[idx];
    }
    const int nb = blockIdx.x * 32;
    for (int f4 = t; f4 < 32 * CIN / 4; f4 += 256) {
        int f = f4 * 4;
        int nl = f / CIN, kk = f % CIN;
        const float4 v = *reinterpret_cast<const float4*>(X + (size_t)(nb + nl) * CIN + kk);
        *reinterpret_cast<float4*>(&sX[nl * STR + kk]) = v;
    }
    __syncthreads();

    const int wave = t >> 6, lane = t & 63;
    const int n0 = wave * 8;
    float acc[8] = {0.f,0.f,0.f,0.f,0.f,0.f,0.f,0.f};
    for (int kq = 0; kq < CIN; kq += 4) {
        const float4 w4 = *reinterpret_cast<const float4*>(&sW[lane * STR + kq]);
        #pragma unroll
        for (int n = 0; n < 8; n++) {
            const float4 x4 = *reinterpret_cast<const float4*>(&sX[(n0 + n) * STR + kq]);
            acc[n] += w4.x * x4.x + w4.y * x4.y + w4.z * x4.z + w4.w * x4.w;
        }
    }
    #pragma unroll
    for (int n = 0; n < 8; n++) {
        H[(size_t)(nb + n0 + n) * 64 + lane] = acc[n] * dinv[nb + n0 + n];
    }
}

// ---------------- propagation: Hout[v] = dinv[v] * sum_e Hin[row_e] + bias ----------------
// one wave per node, lane = channel. CSR segments padded to x8 with sentinel
// zero-row, so the loop is branch-free with 8 independent gathers in flight.

__global__ __launch_bounds__(256) void k_prop(const float* __restrict__ Hin,
                                              const int* __restrict__ csr,
                                              const int* __restrict__ offs,
                                              const int* __restrict__ deg,
                                              const float* __restrict__ dinv,
                                              const float* __restrict__ bias,
                                              float* __restrict__ Hout) {
    const int wave = threadIdx.x >> 6, lane = threadIdx.x & 63;
    const int v = blockIdx.x * 4 + wave;
    if (v >= N_NODES) return;
    const int start = offs[v];                 // multiple of 8 -> 32B aligned
    const int cntp = (deg[v] + 7) & ~7;
    const int* ep = csr + start;
    float acc = 0.f;
    for (int j = 0; j < cntp; j += 8) {
        const int4 q0 = *reinterpret_cast<const int4*>(ep + j);
        const int4 q1 = *reinterpret_cast<const int4*>(ep + j + 4);
        float s0 = Hin[(size_t)q0.x * 64 + lane];
        float s1 = Hin[(size_t)q0.y * 64 + lane];
        float s2 = Hin[(size_t)q0.z * 64 + lane];
        float s3 = Hin[(size_t)q0.w * 64 + lane];
        float s4 = Hin[(size_t)q1.x * 64 + lane];
        float s5 = Hin[(size_t)q1.y * 64 + lane];
        float s6 = Hin[(size_t)q1.z * 64 + lane];
        float s7 = Hin[(size_t)q1.w * 64 + lane];
        acc += ((s0 + s1) + (s2 + s3)) + ((s4 + s5) + (s6 + s7));
    }
    Hout[(size_t)v * 64 + lane] = dinv[v] * acc + bias[lane];
}

// ---------------- pooling ----------------

__global__ void k_pool(const float* __restrict__ H, const int* __restrict__ batch,
                       float* __restrict__ gsums) {
    const int gw = (blockIdx.x * blockDim.x + threadIdx.x) >> 6;
    const int lane = threadIdx.x & 63;
    const int nwaves = (gridDim.x * blockDim.x) >> 6;
    const int chunk = (N_NODES + nwaves - 1) / nwaves;
    int v0 = gw * chunk;
    int v1 = min(v0 + chunk, N_NODES);
    if (v0 >= v1) return;
    float acc = 0.f;
    int cur = batch[v0];
    for (int v = v0; v < v1; v++) {
        int g = batch[v];
        if (g != cur) {
            atomicAdd(&gsums[cur * 64 + lane], acc);
            acc = 0.f; cur = g;
        }
        acc += H[(size_t)v * 64 + lane];
    }
    atomicAdd(&gsums[cur * 64 + lane], acc);
}

__global__ void k_final(const float* __restrict__ gsums, const int* __restrict__ batch,
                        const float* __restrict__ Wl, const float* __restrict__ bl,
                        float* __restrict__ out) {
    __shared__ int scnt[128];
    int t = threadIdx.x;
    // count nodes in graph t via binary search (batch is sorted)
    int lo = 0, hi = N_NODES;
    while (lo < hi) { int mid = (lo + hi) >> 1; if (batch[mid] < t) lo = mid + 1; else hi = mid; }
    int a = lo;
    lo = 0; hi = N_NODES;
    while (lo < hi) { int mid = (lo + hi) >> 1; if (batch[mid] < t + 1) lo = mid + 1; else hi = mid; }
    scnt[t] = lo - a;
    __syncthreads();
    for (int off = 64; off > 0; off >>= 1) {
        if (t < off) scnt[t] = max(scnt[t], scnt[t + off]);
        __syncthreads();
    }
    float nmax = (float)scnt[0];
    float s = 0.f;
    for (int c = 0; c < 64; c++) s += gsums[(size_t)t * 64 + c] * Wl[c];
    out[t] = s / nmax + bl[0];
}

// ---------------- launch ----------------

extern "C" void kernel_launch(void* const* d_in, const int* in_sizes, int n_in,
                              void* d_out, int out_size, void* d_ws, size_t ws_size,
                              hipStream_t stream) {
    const float* x    = (const float*)d_in[0];
    const int*   ei   = (const int*)d_in[1];     // [2, E] int32
    const int*   batch= (const int*)d_in[2];
    const float* W1 = (const float*)d_in[3];  const float* b1 = (const float*)d_in[4];
    const float* W2 = (const float*)d_in[5];  const float* b2 = (const float*)d_in[6];
    const float* W3 = (const float*)d_in[7];  const float* b3 = (const float*)d_in[8];
    const float* W4 = (const float*)d_in[9];  const float* b4 = (const float*)d_in[10];
    const float* Wl = (const float*)d_in[11]; const float* bl = (const float*)d_in[12];
    float* out = (float*)d_out;

    const int* row = ei;
    const int* col = ei + N_EDGES;

    // workspace layout (256B aligned blocks)
    char* ws = (char*)d_ws;
    size_t off = 0;
    auto alloc = [&](size_t bytes) {
        void* p = ws + off;
        off = (off + bytes + 255) & ~(size_t)255;
        return p;
    };
    int*   deg     = (int*)alloc(N_NODES * 4);
    int*   offs    = (int*)alloc(N_NODES * 4);
    int*   cursor  = (int*)alloc(N_NODES * 4);
    float* dinv    = (float*)alloc(N_NODES * 4);
    int*   bsums   = (int*)alloc(512 * 4);
    int*   csr     = (int*)alloc(((size_t)N_EDGES + 8 * N_NODES) * 4);  // padded
    float* h_a     = (float*)alloc((size_t)(N_NODES + 1) * 64 * 4);     // +1 zero row
    float* h_b     = (float*)alloc((size_t)(N_NODES + 1) * 64 * 4);
    float* gsums   = (float*)alloc(N_GRAPHS * 64 * 4);

    const int SCAN_BLOCKS = (N_NODES + 255) / 256;   // 391

    hipMemsetAsync(deg, 0, N_NODES * 4, stream);
    hipMemsetAsync(gsums, 0, N_GRAPHS * 64 * 4, stream);
    // zero the sentinel rows (index N_NODES) of both feature buffers
    hipMemsetAsync(h_a + (size_t)N_NODES * 64, 0, 64 * 4, stream);
    hipMemsetAsync(h_b + (size_t)N_NODES * 64, 0, 64 * 4, stream);

    k_count<<<(N_EDGES + 255) / 256, 256, 0, stream>>>(col, deg);
    k_scan1<<<SCAN_BLOCKS, 256, 0, stream>>>(deg, offs, bsums);
    k_scan2<<<1, 512, 0, stream>>>(bsums, SCAN_BLOCKS);
    k_scan3<<<SCAN_BLOCKS, 256, 0, stream>>>(offs, bsums, deg, cursor, dinv, csr);
    k_scatter<<<(N_EDGES + 255) / 256, 256, 0, stream>>>(row, col, cursor, csr);

    // layer 1: h_a = dinv * (x @ W1) ; h_b = dinv * prop(h_a) + b1
    k_gemm<128><<<N_NODES / 32, 256, 0, stream>>>(x, W1, dinv, h_a);
    k_prop<<<N_NODES / 4, 256, 0, stream>>>(h_a, csr, offs, deg, dinv, b1, h_b);
    // layer 2
    k_gemm<64><<<N_NODES / 32, 256, 0, stream>>>(h_b, W2, dinv, h_a);
    k_prop<<<N_NODES / 4, 256, 0, stream>>>(h_a, csr, offs, deg, dinv, b2, h_b);
    // layer 3
    k_gemm<64><<<N_NODES / 32, 256, 0, stream>>>(h_b, W3, dinv, h_a);
    k_prop<<<N_NODES / 4, 256, 0, stream>>>(h_a, csr, offs, deg, dinv, b3, h_b);
    // layer 4
    k_gemm<64><<<N_NODES / 32, 256, 0, stream>>>(h_b, W4, dinv, h_a);
    k_prop<<<N_NODES / 4, 256, 0, stream>>>(h_a, csr, offs, deg, dinv, b4, h_b);

    // pooling + readout
    k_pool<<<98, 256, 0, stream>>>(h_b, batch, gsums);
    k_final<<<1, 128, 0, stream>>>(gsums, batch, Wl, bl, out);
}